// Round 5
// baseline (362.367 us; speedup 1.0000x reference)
//
#include <hip/hip_runtime.h>
#include <hip/hip_fp16.h>

// CTC forward loss. B=64, T=2000, C=128 (blank=127), Lmax=200, S=401.
//  K1 (parallel): softmax + gather-to-label-space. Writes packed fp16 rows to
//      d_ws: per (b,t) 544 B = [204 label probs | blank @408 | pad | 64 halo
//      probs @416 (halo k = q(lab[4k-1]))]. 64*2000*544 = 69.6 MB.
//  K2 (serial, 1 wave/b): alpha recursion in linear domain + per-lane pow2
//      exponent tracking. Rows staged 16/chunk via global_load_lds (double
//      buffer; barrier drains chunk-old loads - R3-proven decoupling). Round
//      (2 steps): 2x ds_read_b64 + 2 blank + 1 halo (<=2-way conflicts, free)
//      + 3 boundary shuffles; E-shuffle/corr only after renorms (every 8 steps).

#define LOG2E 1.44269504088896340736f
#define LN2F  0.69314718055994530942f

namespace {

constexpr int Bc = 64, Tc = 2000, Cc = 128, Lmaxc = 200;
constexpr int ROWB = 544;          // packed row bytes (16-divisible)
constexpr int CH = 16;             // rows per chunk
constexpr int LDSB = 9216;         // 9 x 1024 (16B x 64 lanes) covers 16*544=8704

typedef const __attribute__((address_space(1))) void* gas_ptr;
typedef __attribute__((address_space(3))) void* las_ptr;

// ---------------- Kernel 1: softmax + gather -> packed fp16 rows ------------
__global__ __launch_bounds__(256) void pack_kernel(
    const float* __restrict__ y, const int* __restrict__ y_true,
    __half* __restrict__ W) {
  const int b = blockIdx.y;            // 64
  const int g = blockIdx.x;            // 10
  const int wv = threadIdx.x >> 6, lane = threadIdx.x & 63;
  const int* labs = y_true + b * Lmaxc;
  auto labc = [&](int l) -> int {
    int lc = l < 0 ? 0 : (l > Lmaxc - 1 ? Lmaxc - 1 : l);
    int c = labs[lc];
    return c < 0 ? 0 : c;  // ref maps padded -1 -> 0
  };
  const int cA0 = labc(2 * lane), cA1 = labc(2 * lane + 1);
  const int cB0 = labc(128 + 2 * lane), cB1 = labc(129 + 2 * lane);
  const int cH0 = labc(8 * lane - 1), cH1 = labc(8 * lane + 3);
  __shared__ float scr[4][128];
  float* ms = scr[wv];
  const float* yb = y + (size_t)b * Tc * Cc;
  char* Wb = (char*)W + (size_t)b * Tc * ROWB;
  const int t0 = g * 200 + wv * 50;
  for (int i = 0; i < 50; ++i) {
    const int t = t0 + i;
    float2 yy = *(const float2*)(yb + (size_t)t * Cc + 2 * lane);
    float e0 = exp2f(fminf(yy.x * LOG2E, 50.f));
    float e1 = exp2f(fminf(yy.y * LOG2E, 50.f));
    float s = e0 + e1;
#pragma unroll
    for (int m = 1; m < 64; m <<= 1) s += __shfl_xor(s, m, 64);
    float rs = 1.0f / s;
    *(float2*)(ms + 2 * lane) = make_float2(e0, e1);
    // wave-synchronous: per-wave DS ops are in-order; no barrier needed
    float v0 = ms[cA0], v1 = ms[cA1], v2 = ms[cB0], v3 = ms[cB1];
    float h0 = ms[cH0], h1 = ms[cH1];
    float bl = __int_as_float(__builtin_amdgcn_readlane(__float_as_int(e1), 63));
    char* Wr = Wb + (size_t)t * ROWB;
    *(__half2*)(Wr + 4 * lane) = __floats2half2_rn(v0 * rs, v1 * rs);
    if (lane < 38) *(__half2*)(Wr + 256 + 4 * lane) = __floats2half2_rn(v2 * rs, v3 * rs);
    if (lane < 32) *(__half2*)(Wr + 416 + 4 * lane) = __floats2half2_rn(h0 * rs, h1 * rs);
    if (lane == 38) *(__half2*)(Wr + 408) = __floats2half2_rn(bl * rs, 0.f);
  }
}

// ---------------- Kernel 2: alpha recursion, one wave per b -----------------
__global__ __launch_bounds__(64) void ctc_alpha_kernel(
    const __half* __restrict__ W, const int* __restrict__ y_true,
    const int* __restrict__ in_len, const int* __restrict__ lab_len,
    float* __restrict__ out) {
  __shared__ __align__(16) char buf[2][LDSB];
  const int b = blockIdx.x, lane = threadIdx.x;
  int len = in_len[b];
  len = len < 1 ? 1 : (len > Tc ? Tc : len);
  const int ll = lab_len[b];
  const int* labs = y_true + b * Lmaxc;
  auto labc = [&](int l) -> int {
    int lc = l < 0 ? 0 : (l > Lmaxc - 1 ? Lmaxc - 1 : l);
    int c = labs[lc];
    return c < 0 ? 0 : c;
  };
  const int c0i = labc(4 * lane), c1i = labc(4 * lane + 1);
  const int c2i = labc(4 * lane + 2), c3i = labc(4 * lane + 3);
  const int cm1 = labc(4 * lane - 1), cm2 = labc(4 * lane - 2);
  const float sk0 = (4 * lane >= 1 && c0i != cm1) ? 1.f : 0.f;
  const float sk1 = (c1i != c0i) ? 1.f : 0.f;
  const float sk2 = (c2i != c1i) ? 1.f : 0.f;
  const float sk3 = (c3i != c2i) ? 1.f : 0.f;
  const float skH = (lane >= 1 && cm1 != cm2) ? 1.f : 0.f;
  const int lane8 = 8 * lane, lane2 = 2 * lane;

  const char* Wb = (const char*)W + (size_t)b * Tc * ROWB;
  const unsigned maxoff = (unsigned)Tc * ROWB - 16;
  auto load_chunk = [&](int bufi, int k) {
#pragma unroll
    for (int j = 0; j < 9; ++j) {
      unsigned off = (unsigned)(1 + CH * k) * ROWB + j * 1024 + lane * 16;
      off = off > maxoff ? maxoff : off;
      __builtin_amdgcn_global_load_lds((gas_ptr)(Wb + off),
                                       (las_ptr)(&buf[bufi][j * 1024]), 16, 0, 0);
    }
  };
  // rw is compile-time in the unrolled loop -> rw*ROWB folds into DS offsets.
  auto rdA = [&](const char* base, int rw, float4& q4, float& qb, float& qh) {
    const char* r = base + rw * ROWB;
    uint2 u = *(const uint2*)(r + lane8);
    float2 flo = __half22float2(*(__half2*)&u.x);
    float2 fhi = __half22float2(*(__half2*)&u.y);
    q4 = make_float4(flo.x, flo.y, fhi.x, fhi.y);
    qb = __half2float(*(const __half*)(r + 408));
    qh = __half2float(*(const __half*)(r + 416 + lane2));
  };
  auto rdB = [&](const char* base, int rw, float4& q4, float& qb) {
    const char* r = base + rw * ROWB;
    uint2 u = *(const uint2*)(r + lane8);
    float2 flo = __half22float2(*(__half2*)&u.x);
    float2 fhi = __half22float2(*(__half2*)&u.y);
    q4 = make_float4(flo.x, flo.y, fhi.x, fhi.y);
    qb = __half2float(*(const __half*)(r + 408));
  };

  float a[8];
#pragma unroll
  for (int j = 0; j < 8; ++j) a[j] = 0.0f;
  int E = 0;
  {  // seed from row t=0 (direct global, once)
    float l0 = __half2float(*(const __half*)(Wb + 0));
    float b0 = __half2float(*(const __half*)(Wb + 408));
    if (lane == 0) { a[0] = b0; a[1] = l0; }
  }
  float s7d = __shfl_up(a[7], 1, 64);
  float s6d = __shfl_up(a[6], 1, 64);
  float s5d = __shfl_up(a[5], 1, 64);
  int epd = 0;
  float corr = (lane == 0) ? 0.f : 1.f;

  const int NR = len - 1;                  // rows t=1..len-1
  const int NCg = (NR + CH - 1) / CH;      // chunks to load
  const int cfull = NR / CH;               // full chunks
  if (NCg > 0) load_chunk(0, 0);

  for (int c = 0; c < cfull; ++c) {
    __syncthreads();  // drains loads for chunk c (issued one chunk ago)
    if (c + 1 < NCg) load_chunk((c + 1) & 1, c + 1);
    const char* base = buf[c & 1];
    float4 q4A[2], q4B[2];
    float qbA[2], qbB[2], qhA[2];
    rdA(base, 0, q4A[0], qbA[0], qhA[0]);   // once-per-chunk bubble (~120 cyc)
    rdB(base, 1, q4B[0], qbB[0]);
#pragma unroll
    for (int rr = 0; rr < 8; ++rr) {
      const int p = rr & 1, pn = p ^ 1;
      if (rr < 7) {  // prefetch next round (stays within this chunk)
        rdA(base, 2 * rr + 2, q4A[pn], qbA[pn], qhA[pn]);
        rdB(base, 2 * rr + 3, q4B[pn], qbB[pn]);
      }
      const float bA = qbA[p], bB = qbB[p];
      // step t: boundary-free parts first
      float n2 = (a[2] + a[1]) * bA;
      float n3 = (a[3] + a[2] + sk1 * a[1]) * q4A[p].y;
      float n4 = (a[4] + a[3]) * bA;
      float n5 = (a[5] + a[4] + sk2 * a[3]) * q4A[p].z;
      float n6 = (a[6] + a[5]) * bA;
      float n7 = (a[7] + a[6] + sk3 * a[5]) * q4A[p].w;
      // step t+1: boundary-free parts
      float m4 = (n4 + n3) * bB;
      float m5 = (n5 + n4 + sk2 * n3) * q4B[p].z;
      float m6 = (n6 + n5) * bB;
      float m7 = (n7 + n6 + sk3 * n5) * q4B[p].w;
      // consume delayed neighbor boundary (corr fixed between renorms)
      float w7 = s7d * corr, w6 = s6d * corr, w5 = s5d * corr;
      float hA = (w7 + w6 + skH * w5) * qhA[p];
      float n0 = (a[0] + w7) * bA;
      float n1 = (a[1] + a[0] + sk0 * w7) * q4A[p].x;
      float m0 = (n0 + hA) * bB;
      float m1 = (n1 + n0 + sk0 * hA) * q4B[p].x;
      float m2 = (n2 + n1) * bB;
      float m3 = (n3 + n2 + sk1 * n1) * q4B[p].y;
      a[0] = m0; a[1] = m1; a[2] = m2; a[3] = m3;
      a[4] = m4; a[5] = m5; a[6] = m6; a[7] = m7;
      if (rr == 3 || rr == 7) {  // renorm every 8 steps (exact pow2)
        float mx = fmaxf(fmaxf(fmaxf(a[0], a[1]), fmaxf(a[2], a[3])),
                         fmaxf(fmaxf(a[4], a[5]), fmaxf(a[6], a[7])));
        unsigned bits = __float_as_uint(mx);
        bool z = (bits == 0u);
        int e = (int)(bits >> 23) - 127;
        float f = __uint_as_float((254u - (bits >> 23)) << 23);  // 2^-e
        f = z ? 1.0f : f;
#pragma unroll
        for (int j = 0; j < 8; ++j) a[j] *= f;
        E = z ? epd : (E + e);
      }
      s7d = __shfl_up(a[7], 1, 64);
      s6d = __shfl_up(a[6], 1, 64);
      s5d = __shfl_up(a[5], 1, 64);
      if (rr == 3 || rr == 7) {  // E changes only at renorm -> refresh corr
        epd = __shfl_up(E, 1, 64);
        int de = epd - E;
        de = de < -126 ? -126 : (de > 60 ? 60 : de);
        corr = __int_as_float((de + 127) << 23);
        corr = (lane == 0) ? 0.0f : corr;
      }
    }
  }

  // tail: remaining rows of partial chunk cfull, single-step from LDS
  const int rem = NR - cfull * CH;
  if (rem > 0) {
    __syncthreads();
    const char* base = buf[cfull & 1];
    for (int r = 0; r < rem; ++r) {
      const char* rp = base + r * ROWB;
      uint2 u = *(const uint2*)(rp + lane8);
      float2 flo = __half22float2(*(__half2*)&u.x);
      float2 fhi = __half22float2(*(__half2*)&u.y);
      float bl = __half2float(*(const __half*)(rp + 408));
      float s7 = __shfl_up(a[7], 1, 64);
      int ep = __shfl_up(E, 1, 64);
      int de = ep - E;
      de = de < -126 ? -126 : (de > 60 ? 60 : de);
      float c2 = __int_as_float((de + 127) << 23);
      c2 = (lane == 0) ? 0.0f : c2;
      float w7 = s7 * c2;
      float n0 = (a[0] + w7) * bl;
      float n1 = (a[1] + a[0] + sk0 * w7) * flo.x;
      float n2 = (a[2] + a[1]) * bl;
      float n3 = (a[3] + a[2] + sk1 * a[1]) * flo.y;
      float n4 = (a[4] + a[3]) * bl;
      float n5 = (a[5] + a[4] + sk2 * a[3]) * fhi.x;
      float n6 = (a[6] + a[5]) * bl;
      float n7 = (a[7] + a[6] + sk3 * a[5]) * fhi.y;
      a[0] = n0; a[1] = n1; a[2] = n2; a[3] = n3;
      a[4] = n4; a[5] = n5; a[6] = n6; a[7] = n7;
      if ((r & 3) == 3) {
        float mx = fmaxf(fmaxf(fmaxf(a[0], a[1]), fmaxf(a[2], a[3])),
                         fmaxf(fmaxf(a[4], a[5]), fmaxf(a[6], a[7])));
        unsigned bits = __float_as_uint(mx);
        bool z = (bits == 0u);
        int e = (int)(bits >> 23) - 127;
        float f = __uint_as_float((254u - (bits >> 23)) << 23);
        f = z ? 1.0f : f;
#pragma unroll
        for (int j = 0; j < 8; ++j) a[j] *= f;
        E = z ? ep : (E + e);
      }
    }
  }

  // final combine: loss = -lse(alpha[2ll], alpha[2ll-1]) in log2 domain
  int sE = 2 * ll;
  int sP = sE - 1 < 0 ? 0 : sE - 1;
  int laneA = sE >> 3, jA = sE & 7;
  int laneB = sP >> 3, jB = sP & 7;
  float va = a[0];
  if (jA == 1) va = a[1];
  if (jA == 2) va = a[2];
  if (jA == 3) va = a[3];
  if (jA == 4) va = a[4];
  if (jA == 5) va = a[5];
  if (jA == 6) va = a[6];
  if (jA == 7) va = a[7];
  float vb = a[0];
  if (jB == 1) vb = a[1];
  if (jB == 2) vb = a[2];
  if (jB == 3) vb = a[3];
  if (jB == 4) vb = a[4];
  if (jB == 5) vb = a[5];
  if (jB == 6) vb = a[6];
  if (jB == 7) vb = a[7];
  float aA = __int_as_float(__builtin_amdgcn_ds_bpermute(laneA << 2, __float_as_int(va)));
  float aB = __int_as_float(__builtin_amdgcn_ds_bpermute(laneB << 2, __float_as_int(vb)));
  int EA = __builtin_amdgcn_ds_bpermute(laneA << 2, E);
  int EB = __builtin_amdgcn_ds_bpermute(laneB << 2, E);
  if (lane == 0) {
    float l1 = (aA > 0.0f) ? (float)EA + log2f(aA) : -1e30f;
    float l2 = (aB > 0.0f) ? (float)EB + log2f(aB) : -1e30f;
    float mm = fmaxf(l1, l2);
    float v = mm + log2f(exp2f(l1 - mm) + exp2f(l2 - mm));
    out[b] = -v * LN2F;
  }
}

}  // namespace

extern "C" void kernel_launch(void* const* d_in, const int* in_sizes, int n_in,
                              void* d_out, int out_size, void* d_ws, size_t ws_size,
                              hipStream_t stream) {
  const float* y = (const float*)d_in[0];   // [64,2000,128] f32
  const int* yt = (const int*)d_in[1];      // [64,200] i32
  const int* il = (const int*)d_in[2];      // [64] i32
  const int* lb = (const int*)d_in[3];      // [64] i32
  float* out = (float*)d_out;               // [64] f32
  __half* W = (__half*)d_ws;                // 64*2000*544 B = 69.6 MB

  hipLaunchKernelGGL(pack_kernel, dim3(10, 64), dim3(256), 0, stream, y, yt, W);
  hipLaunchKernelGGL(ctc_alpha_kernel, dim3(Bc), dim3(64), 0, stream,
                     W, yt, il, lb, out);
}

// Round 7
// 268.795 us; speedup vs baseline: 1.3481x; 1.3481x over previous
//
#include <hip/hip_runtime.h>
#include <hip/hip_fp16.h>

// CTC forward loss. B=64, T=2000, C=128 (blank=127), Lmax=200, S=401.
//  K1 (parallel): softmax + gather-to-label-space via register bpermute (no
//      LDS scratch). Packed fp16 rows in d_ws: 416 B = [204 label probs |
//      blank @408 | pad]. 64*2000*416 = 53.2 MB.
//  K2 (serial, 1 wave/b): alpha recursion, linear domain + per-lane pow2
//      exponent tracking. KEY CHANGE vs R5: all cross-lane boundary traffic
//      (a5,a6,a7,E, halo-q) moved from ds_permute shuffles (~120cyc DS pipe,
//      the measured ~300-400 cyc/round floor) to DPP wave_shr:1 (VALU pipe,
//      ~8 cyc). Only DS left: 4 reads/round, prefetched 2 rounds deep from
//      LDS chunks staged by global_load_lds (32 rows, double buffer).

#define LOG2E 1.44269504088896340736f
#define LN2F  0.69314718055994530942f

namespace {

constexpr int Bc = 64, Tc = 2000, Cc = 128, Lmaxc = 200;
constexpr int ROWB = 416;            // 204*2 + blank@408 + pad, 16-divisible
constexpr int CH = 32;               // rows per chunk
constexpr int CHB = CH * ROWB;       // 13312 = 13*1024
constexpr int BUFB = CHB + 1024;     // +1 KB pad load (real data, no junk NaN)

typedef const __attribute__((address_space(1))) void* gas_ptr;
typedef __attribute__((address_space(3))) void* las_ptr;

__device__ __forceinline__ float dpp_shr1_f(float x) {  // lane i <- lane i-1, lane0 <- 0
  return __int_as_float(
      __builtin_amdgcn_update_dpp(0, __float_as_int(x), 0x138, 0xF, 0xF, true));
}
__device__ __forceinline__ int dpp_shr1_i(int x) {
  return __builtin_amdgcn_update_dpp(0, x, 0x138, 0xF, 0xF, true);
}
template <int CTRL>
__device__ __forceinline__ float dpp_ctrl_add(float v) {
  return v + __int_as_float(
      __builtin_amdgcn_update_dpp(0, __float_as_int(v), CTRL, 0xF, 0xF, true));
}

// ---------------- Kernel 1: softmax + bpermute gather -> packed rows --------
__global__ __launch_bounds__(256) void pack_kernel(
    const float* __restrict__ y, const int* __restrict__ y_true,
    __half* __restrict__ W) {
  const int b = blockIdx.y;
  const int wv = threadIdx.x >> 6, lane = threadIdx.x & 63;
  const int* labs = y_true + b * Lmaxc;
  auto labc = [&](int l) -> int {
    int lc = l < 0 ? 0 : (l > Lmaxc - 1 ? Lmaxc - 1 : l);
    int c = labs[lc];
    return c < 0 ? 0 : c;  // ref maps padded -1 -> 0
  };
  const int cA0 = labc(2 * lane), cA1 = labc(2 * lane + 1);
  const int cB0 = labc(128 + 2 * lane), cB1 = labc(129 + 2 * lane);
  const float* yb = y + (size_t)b * Tc * Cc;
  char* Wb = (char*)W + (size_t)b * Tc * ROWB;

  for (int t = blockIdx.x * 4 + wv; t < Tc; t += 64) {
    float2 yy = *(const float2*)(yb + (size_t)t * Cc + 2 * lane);
    float e0 = exp2f(fminf(yy.x * LOG2E, 50.f));
    float e1 = exp2f(fminf(yy.y * LOG2E, 50.f));
    // full-wave sum via DPP (row_shr 1,2,4,8; row_bcast15; row_bcast31) -> lane 63
    float v = e0 + e1;
    v = dpp_ctrl_add<0x111>(v);
    v = dpp_ctrl_add<0x112>(v);
    v = dpp_ctrl_add<0x114>(v);
    v = dpp_ctrl_add<0x118>(v);
    v = dpp_ctrl_add<0x142>(v);
    v = dpp_ctrl_add<0x143>(v);
    float stot = __int_as_float(__builtin_amdgcn_readlane(__float_as_int(v), 63));
    float rs = 1.0f / stot;
    // per-lane classes (2lane, 2lane+1) packed as half2 -> gather by bpermute
    unsigned q2 = __builtin_bit_cast(unsigned, __floats2half2_rn(e0 * rs, e1 * rs));
    unsigned gA0 = (unsigned)__builtin_amdgcn_ds_bpermute((cA0 >> 1) << 2, (int)q2);
    unsigned gA1 = (unsigned)__builtin_amdgcn_ds_bpermute((cA1 >> 1) << 2, (int)q2);
    unsigned gB0 = (unsigned)__builtin_amdgcn_ds_bpermute((cB0 >> 1) << 2, (int)q2);
    unsigned gB1 = (unsigned)__builtin_amdgcn_ds_bpermute((cB1 >> 1) << 2, (int)q2);
    unsigned hA0 = (cA0 & 1) ? (gA0 >> 16) : (gA0 & 0xFFFFu);
    unsigned hA1 = (cA1 & 1) ? (gA1 >> 16) : (gA1 & 0xFFFFu);
    unsigned hB0 = (cB0 & 1) ? (gB0 >> 16) : (gB0 & 0xFFFFu);
    unsigned hB1 = (cB1 & 1) ? (gB1 >> 16) : (gB1 & 0xFFFFu);
    char* Wr = Wb + (size_t)t * ROWB;
    *(unsigned*)(Wr + 4 * lane) = hA0 | (hA1 << 16);
    if (lane < 38) *(unsigned*)(Wr + 256 + 4 * lane) = hB0 | (hB1 << 16);
    if (lane == 0) {
      unsigned bl = (unsigned)__builtin_amdgcn_readlane((int)q2, 63) >> 16;  // class 127
      *(unsigned short*)(Wr + 408) = (unsigned short)bl;
      *(unsigned short*)(Wr + 410) = 0;
      *(unsigned*)(Wr + 412) = 0;
    }
  }
}

// ---------------- Kernel 2: alpha recursion, one wave per b -----------------
__global__ __launch_bounds__(64) void ctc_alpha_kernel(
    const __half* __restrict__ W, const int* __restrict__ y_true,
    const int* __restrict__ in_len, const int* __restrict__ lab_len,
    float* __restrict__ out) {
  __shared__ __align__(16) char buf[2][BUFB];
  const int b = blockIdx.x, lane = threadIdx.x;
  int len = in_len[b];
  len = len < 1 ? 1 : (len > Tc ? Tc : len);
  const int ll = lab_len[b];
  const int* labs = y_true + b * Lmaxc;
  auto labc = [&](int l) -> int {
    int lc = l < 0 ? 0 : (l > Lmaxc - 1 ? Lmaxc - 1 : l);
    int c = labs[lc];
    return c < 0 ? 0 : c;
  };
  const int c0i = labc(4 * lane), c1i = labc(4 * lane + 1);
  const int c2i = labc(4 * lane + 2), c3i = labc(4 * lane + 3);
  const int cm1 = labc(4 * lane - 1), cm2 = labc(4 * lane - 2);
  const float sk0 = (4 * lane >= 1 && c0i != cm1) ? 1.f : 0.f;
  const float sk1 = (c1i != c0i) ? 1.f : 0.f;
  const float sk2 = (c2i != c1i) ? 1.f : 0.f;
  const float sk3 = (c3i != c2i) ? 1.f : 0.f;
  const float skH = (lane >= 1 && cm1 != cm2) ? 1.f : 0.f;
  const int lane8 = 8 * lane;

  const char* Wb = (const char*)W + (size_t)b * Tc * ROWB;
  const unsigned maxoff = (unsigned)Tc * ROWB - 16;
  auto load_chunk = [&](int bufi, int k) {
#pragma unroll
    for (int j = 0; j < 14; ++j) {  // 13 data + 1 pad (real next-rows data)
      unsigned off = (unsigned)(1 + CH * k) * ROWB + j * 1024 + lane * 16;
      off = off > maxoff ? maxoff : off;
      __builtin_amdgcn_global_load_lds((gas_ptr)(Wb + off),
                                       (las_ptr)(&buf[bufi][j * 1024]), 16, 0, 0);
    }
  };
  auto rd = [&](const char* base, int row, uint2& lab, unsigned short& bl) {
    const char* r = base + row * ROWB;   // row is compile-time under unroll
    lab = *(const uint2*)(r + lane8);    // slots 4lane..4lane+3 (b64, 2-way: free)
    bl = *(const unsigned short*)(r + 408);  // blank (uniform addr: broadcast)
  };

  float a0 = 0.f, a1 = 0.f, a2 = 0.f, a3 = 0.f;
  float a4 = 0.f, a5 = 0.f, a6 = 0.f, a7 = 0.f;
  int E = 0;
  {  // seed from row t=0 (direct global, once)
    float l0 = __half2float(*(const __half*)(Wb + 0));
    float b0 = __half2float(*(const __half*)(Wb + 408));
    if (lane == 0) { a0 = b0; a1 = l0; }
  }
  float s7d = dpp_shr1_f(a7), s6d = dpp_shr1_f(a6), s5d = dpp_shr1_f(a5);
  int epd = 0;
  float corr = (lane == 0) ? 0.f : 1.f;

  const int NR = len - 1;                 // rows t = 1..len-1
  const int NCg = (NR + CH - 1) / CH;     // chunks to load
  const int cfull = NR / CH;              // full chunks
  if (NCg > 0) load_chunk(0, 0);

  for (int c = 0; c < cfull; ++c) {
    __syncthreads();  // single wave: drains chunk-old global_load_lds (cheap)
    if (c + 1 < NCg) load_chunk((c + 1) & 1, c + 1);
    const char* base = buf[c & 1];
    uint2 labA[3], labB[3];
    unsigned short blA[3], blB[3];
    rd(base, 0, labA[0], blA[0]);
    rd(base, 1, labB[0], blB[0]);
    rd(base, 2, labA[1], blA[1]);
    rd(base, 3, labB[1], blB[1]);
#pragma unroll
    for (int rr = 0; rr < 16; ++rr) {
      const int p = rr % 3, pf = (rr + 2) % 3;
      if (rr < 14) {  // prefetch 2 rounds ahead (stays within this chunk)
        rd(base, 2 * rr + 4, labA[pf], blA[pf]);
        rd(base, 2 * rr + 5, labB[pf], blB[pf]);
      }
      const float2 aLo = __half22float2(*(__half2*)&labA[p].x);
      const float2 aHi = __half22float2(*(__half2*)&labA[p].y);
      const float2 bLo = __half22float2(*(__half2*)&labB[p].x);
      const float2 bHi = __half22float2(*(__half2*)&labB[p].y);
      const float qbA = __half2float(*(__half*)&blA[p]);
      const float qbB = __half2float(*(__half*)&blB[p]);
      const float qhA = dpp_shr1_f(aHi.y);  // halo pos 8L-1 label prob (VALU!)
      const float w7 = s7d * corr, w6 = s6d * corr, w5 = s5d * corr;
      const float hA = (w7 + w6 + skH * w5) * qhA;
      float n0 = (a0 + w7) * qbA;
      float n1 = (a1 + a0 + sk0 * w7) * aLo.x;
      float n2 = (a2 + a1) * qbA;
      float n3 = (a3 + a2 + sk1 * a1) * aLo.y;
      float n4 = (a4 + a3) * qbA;
      float n5 = (a5 + a4 + sk2 * a3) * aHi.x;
      float n6 = (a6 + a5) * qbA;
      float n7 = (a7 + a6 + sk3 * a5) * aHi.y;
      a0 = (n0 + hA) * qbB;
      a1 = (n1 + n0 + sk0 * hA) * bLo.x;
      a2 = (n2 + n1) * qbB;
      a3 = (n3 + n2 + sk1 * n1) * bLo.y;
      a4 = (n4 + n3) * qbB;
      a5 = (n5 + n4 + sk2 * n3) * bHi.x;
      a6 = (n6 + n5) * qbB;
      a7 = (n7 + n6 + sk3 * n5) * bHi.y;
      if ((rr & 3) == 3) {  // renorm every 8 steps (exact pow2)
        float mx = fmaxf(fmaxf(fmaxf(a0, a1), fmaxf(a2, a3)),
                         fmaxf(fmaxf(a4, a5), fmaxf(a6, a7)));
        unsigned bits = __float_as_uint(mx);
        bool z = (bits == 0u);
        int e = (int)(bits >> 23) - 127;
        float f = __uint_as_float((254u - (bits >> 23)) << 23);  // 2^-e
        f = z ? 1.0f : f;
        a0 *= f; a1 *= f; a2 *= f; a3 *= f;
        a4 *= f; a5 *= f; a6 *= f; a7 *= f;
        E = z ? epd : (E + e);
      }
      s7d = dpp_shr1_f(a7);
      s6d = dpp_shr1_f(a6);
      s5d = dpp_shr1_f(a5);
      if ((rr & 3) == 3) {  // E changes only at renorm -> refresh corr
        epd = dpp_shr1_i(E);
        int de = epd - E;
        de = de < -126 ? -126 : (de > 60 ? 60 : de);
        corr = __int_as_float((de + 127) << 23);
        corr = (lane == 0) ? 0.0f : corr;
      }
    }
  }

  // tail: remaining rows of partial chunk cfull, single-step from LDS
  const int rem = NR - cfull * CH;
  if (rem > 0) {
    __syncthreads();
    const char* base = buf[cfull & 1];
    for (int r = 0; r < rem; ++r) {
      const char* rp = base + r * ROWB;
      uint2 lab = *(const uint2*)(rp + lane8);
      float2 flo = __half22float2(*(__half2*)&lab.x);
      float2 fhi = __half22float2(*(__half2*)&lab.y);
      float bl = __half2float(*(const __half*)(rp + 408));
      float s7 = dpp_shr1_f(a7);
      int ep = dpp_shr1_i(E);
      int de = ep - E;
      de = de < -126 ? -126 : (de > 60 ? 60 : de);
      float c2 = __int_as_float((de + 127) << 23);
      c2 = (lane == 0) ? 0.0f : c2;
      float w7 = s7 * c2;
      float n0 = (a0 + w7) * bl;
      float n1 = (a1 + a0 + sk0 * w7) * flo.x;
      float n2 = (a2 + a1) * bl;
      float n3 = (a3 + a2 + sk1 * a1) * flo.y;
      float n4 = (a4 + a3) * bl;
      float n5 = (a5 + a4 + sk2 * a3) * fhi.x;
      float n6 = (a6 + a5) * bl;
      float n7 = (a7 + a6 + sk3 * a5) * fhi.y;
      a0 = n0; a1 = n1; a2 = n2; a3 = n3;
      a4 = n4; a5 = n5; a6 = n6; a7 = n7;
      if ((r & 3) == 3) {
        float mx = fmaxf(fmaxf(fmaxf(a0, a1), fmaxf(a2, a3)),
                         fmaxf(fmaxf(a4, a5), fmaxf(a6, a7)));
        unsigned bits = __float_as_uint(mx);
        bool z = (bits == 0u);
        int e = (int)(bits >> 23) - 127;
        float f = __uint_as_float((254u - (bits >> 23)) << 23);
        f = z ? 1.0f : f;
        a0 *= f; a1 *= f; a2 *= f; a3 *= f;
        a4 *= f; a5 *= f; a6 *= f; a7 *= f;
        E = z ? ep : (E + e);
      }
    }
  }

  // final combine: loss = -lse(alpha[2ll], alpha[2ll-1]) in log2 domain
  int sE = 2 * ll;
  int sP = sE - 1 < 0 ? 0 : sE - 1;
  int laneA = sE >> 3, jA = sE & 7;
  int laneB = sP >> 3, jB = sP & 7;
  float va = a0;
  if (jA == 1) va = a1;
  if (jA == 2) va = a2;
  if (jA == 3) va = a3;
  if (jA == 4) va = a4;
  if (jA == 5) va = a5;
  if (jA == 6) va = a6;
  if (jA == 7) va = a7;
  float vb = a0;
  if (jB == 1) vb = a1;
  if (jB == 2) vb = a2;
  if (jB == 3) vb = a3;
  if (jB == 4) vb = a4;
  if (jB == 5) vb = a5;
  if (jB == 6) vb = a6;
  if (jB == 7) vb = a7;
  float aA = __int_as_float(__builtin_amdgcn_ds_bpermute(laneA << 2, __float_as_int(va)));
  float aB = __int_as_float(__builtin_amdgcn_ds_bpermute(laneB << 2, __float_as_int(vb)));
  int EA = __builtin_amdgcn_ds_bpermute(laneA << 2, E);
  int EB = __builtin_amdgcn_ds_bpermute(laneB << 2, E);
  if (lane == 0) {
    float l1 = (aA > 0.0f) ? (float)EA + log2f(aA) : -1e30f;
    float l2 = (aB > 0.0f) ? (float)EB + log2f(aB) : -1e30f;
    float mm = fmaxf(l1, l2);
    float v = mm + log2f(exp2f(l1 - mm) + exp2f(l2 - mm));
    out[b] = -v * LN2F;
  }
}

}  // namespace

extern "C" void kernel_launch(void* const* d_in, const int* in_sizes, int n_in,
                              void* d_out, int out_size, void* d_ws, size_t ws_size,
                              hipStream_t stream) {
  const float* y = (const float*)d_in[0];   // [64,2000,128] f32
  const int* yt = (const int*)d_in[1];      // [64,200] i32
  const int* il = (const int*)d_in[2];      // [64] i32
  const int* lb = (const int*)d_in[3];      // [64] i32
  float* out = (float*)d_out;               // [64] f32
  __half* W = (__half*)d_ws;                // 64*2000*416 B = 53.2 MB

  hipLaunchKernelGGL(pack_kernel, dim3(16, 64), dim3(256), 0, stream, y, yt, W);
  hipLaunchKernelGGL(ctc_alpha_kernel, dim3(Bc), dim3(64), 0, stream,
                     W, yt, il, lb, out);
}

// Round 8
// 258.868 us; speedup vs baseline: 1.3998x; 1.0383x over previous
//
#include <hip/hip_runtime.h>
#include <hip/hip_fp16.h>

// CTC forward loss. B=64, T=2000, C=128 (blank=127), Lmax=200, S=401.
//  K1 (parallel, 1 wave/row): softmax + gather-to-label-space. Pair layout in
//      d_ws per batch b (stride SB):
//        pair p (steps 2p+1, 2p+2): 1024 B, lane's 16 B =
//          [stepA: h(c0)h(c1)h(c2)h(c3) | stepB: same] (cj = lab[4*lane+j])
//        + f32 blank array blank[t-1] (8 KB region) — pre-converted, t=1..1999.
//  K2 (serial, 1 wave/b): alpha recursion, linear domain + per-lane pow2
//      exponent tracking; boundary via DPP wave_shr (VALU pipe, R7-proven).
//      Round (2 steps) = 1 ds_read_b128 + 1 ds_read_b64 + ~65 VALU. Chunks of
//      16 pairs staged by global_load_lds, double buffer, NO barriers: raw
//      s_waitcnt vmcnt(0) at rr=13 + cross-chunk prefetch at rr=14/15.

#define LOG2E 1.44269504088896340736f
#define LN2F  0.69314718055994530942f

namespace {

constexpr int Bc = 64, Tc = 2000, Cc = 128, Lmaxc = 200;
constexpr int NPAIR = Tc / 2;                // 1000
constexpr int PAIRB = 1024;                  // bytes per pair (64 lanes x 16)
constexpr int BLANKB = 8192;                 // f32 blank region (padded)
constexpr size_t SB = (size_t)NPAIR * PAIRB + BLANKB;  // per-batch stride
constexpr int CHP = 16;                      // pairs per chunk
constexpr int CHB = CHP * PAIRB;             // 16 KB

typedef const __attribute__((address_space(1))) void* gas_ptr;
typedef __attribute__((address_space(3))) void* las_ptr;

__device__ __forceinline__ float dpp_shr1_f(float x) {  // lane i <- i-1, lane0 <- 0
  return __int_as_float(
      __builtin_amdgcn_update_dpp(0, __float_as_int(x), 0x138, 0xF, 0xF, true));
}
__device__ __forceinline__ int dpp_shr1_i(int x) {
  return __builtin_amdgcn_update_dpp(0, x, 0x138, 0xF, 0xF, true);
}
template <int CTRL>
__device__ __forceinline__ float dpp_add(float v) {
  return v + __int_as_float(
      __builtin_amdgcn_update_dpp(0, __float_as_int(v), CTRL, 0xF, 0xF, true));
}
__device__ __forceinline__ float wave_sum_bcast(float v) {  // full-wave sum
  v = dpp_add<0x111>(v);
  v = dpp_add<0x112>(v);
  v = dpp_add<0x114>(v);
  v = dpp_add<0x118>(v);
  v = dpp_add<0x142>(v);
  v = dpp_add<0x143>(v);
  return __int_as_float(__builtin_amdgcn_readlane(__float_as_int(v), 63));
}

// ---------------- Kernel 1: softmax + gather -> pair layout -----------------
__global__ __launch_bounds__(256) void pack_kernel(
    const float* __restrict__ y, const int* __restrict__ y_true,
    char* __restrict__ W) {
  const int b = blockIdx.y;
  const int wv = threadIdx.x >> 6, lane = threadIdx.x & 63;
  const int t = blockIdx.x * 4 + wv;  // grid.x = 500 -> t in [0,2000)
  const int* labs = y_true + b * Lmaxc;
  int base = 4 * lane;
  if (base > Lmaxc - 4) base = Lmaxc - 4;
  const int4 L = *(const int4*)(labs + base);
  auto fix = [&](int v, int idx) {
    int r = (idx > Lmaxc - 1) ? L.w : v;   // labc clamp: idx>199 -> labs[199]
    return r < 0 ? 0 : r;                  // ref maps padded -1 -> 0
  };
  const int c0 = fix(L.x, 4 * lane), c1 = fix(L.y, 4 * lane + 1);
  const int c2 = fix(L.z, 4 * lane + 2), c3 = fix(L.w, 4 * lane + 3);
  const float2 yy = *(const float2*)(y + ((size_t)b * Tc + t) * Cc + 2 * lane);
  float e0 = exp2f(fminf(yy.x * LOG2E, 50.f));
  float e1 = exp2f(fminf(yy.y * LOG2E, 50.f));
  const float rs = 1.0f / wave_sum_bcast(e0 + e1);
  unsigned q2 = __builtin_bit_cast(unsigned, __floats2half2_rn(e0 * rs, e1 * rs));
  unsigned g0 = (unsigned)__builtin_amdgcn_ds_bpermute((c0 >> 1) << 2, (int)q2);
  unsigned g1 = (unsigned)__builtin_amdgcn_ds_bpermute((c1 >> 1) << 2, (int)q2);
  unsigned g2 = (unsigned)__builtin_amdgcn_ds_bpermute((c2 >> 1) << 2, (int)q2);
  unsigned g3 = (unsigned)__builtin_amdgcn_ds_bpermute((c3 >> 1) << 2, (int)q2);
  unsigned h0 = (c0 & 1) ? (g0 >> 16) : (g0 & 0xFFFFu);
  unsigned h1 = (c1 & 1) ? (g1 >> 16) : (g1 & 0xFFFFu);
  unsigned h2 = (c2 & 1) ? (g2 >> 16) : (g2 & 0xFFFFu);
  unsigned h3 = (c3 & 1) ? (g3 >> 16) : (g3 & 0xFFFFu);
  if (t > 0) {
    char* Wb = W + (size_t)b * SB;
    const int pr = (t - 1) >> 1, sl = 1 - (t & 1);  // odd t -> slot 0
    *(uint2*)(Wb + pr * PAIRB + lane * 16 + sl * 8) =
        make_uint2(h0 | (h1 << 16), h2 | (h3 << 16));
    if (lane == 63)  // blank = class 127 prob, pre-converted f32
      *(float*)(Wb + (size_t)NPAIR * PAIRB + (size_t)(t - 1) * 4) = e1 * rs;
  }
}

// ---------------- Kernel 2: alpha recursion, one wave per b -----------------
__global__ __launch_bounds__(64) void ctc_alpha_kernel(
    const float* __restrict__ y, const char* __restrict__ W,
    const int* __restrict__ y_true, const int* __restrict__ in_len,
    const int* __restrict__ lab_len, float* __restrict__ out) {
  __shared__ __align__(16) char bufs[2][CHB];     // 32 KB
  __shared__ __align__(16) float blk_s[BLANKB / 4];  // 8 KB
  const int b = blockIdx.x, lane = threadIdx.x;
  int len = in_len[b];
  len = len < 1 ? 1 : (len > Tc ? Tc : len);
  const int ll = lab_len[b];
  const int* labs = y_true + b * Lmaxc;
  auto labc = [&](int l) -> int {
    int lc = l < 0 ? 0 : (l > Lmaxc - 1 ? Lmaxc - 1 : l);
    int c = labs[lc];
    return c < 0 ? 0 : c;
  };
  const int c0i = labc(4 * lane), c1i = labc(4 * lane + 1);
  const int c2i = labc(4 * lane + 2), c3i = labc(4 * lane + 3);
  const int cm1 = labc(4 * lane - 1), cm2 = labc(4 * lane - 2);
  const float sk0 = (4 * lane >= 1 && c0i != cm1) ? 1.f : 0.f;
  const float sk1 = (c1i != c0i) ? 1.f : 0.f;
  const float sk2 = (c2i != c1i) ? 1.f : 0.f;
  const float sk3 = (c3i != c2i) ? 1.f : 0.f;
  const float skH = (lane >= 1 && cm1 != cm2) ? 1.f : 0.f;
  const int lane16 = lane * 16;

  const char* Wb = W + (size_t)b * SB;
  auto load_pairs = [&](int bi, int k) {
#pragma unroll
    for (int j = 0; j < CHP; ++j) {
      unsigned off = (unsigned)(CHP * k + j) * PAIRB + lane16;
      __builtin_amdgcn_global_load_lds((gas_ptr)(Wb + off),
                                       (las_ptr)(&bufs[bi][j * PAIRB]), 16, 0, 0);
    }
  };
  auto load_blanks = [&]() {
#pragma unroll
    for (int j = 0; j < 8; ++j)
      __builtin_amdgcn_global_load_lds(
          (gas_ptr)(Wb + NPAIR * PAIRB + j * 1024 + lane16),
          (las_ptr)((char*)blk_s + j * 1024), 16, 0, 0);
  };

  float a0 = 0.f, a1 = 0.f, a2 = 0.f, a3 = 0.f;
  float a4 = 0.f, a5 = 0.f, a6 = 0.f, a7 = 0.f;
  int E = 0;
  {  // seed from y row t=0 directly (row 0 is not packed)
    const float* y0 = y + (size_t)b * Tc * Cc + 2 * lane;
    float e0 = exp2f(fminf(y0[0] * LOG2E, 50.f));
    float e1 = exp2f(fminf(y0[1] * LOG2E, 50.f));
    const float rs = 1.0f / wave_sum_bcast(e0 + e1);
    int l0 = labs[0];
    l0 = l0 < 0 ? 0 : l0;
    float ev = (l0 & 1) ? e1 : e0;
    float q0 = __int_as_float(__builtin_amdgcn_readlane(__float_as_int(ev), l0 >> 1)) * rs;
    float qb = __int_as_float(__builtin_amdgcn_readlane(__float_as_int(e1), 63)) * rs;
    if (lane == 0) { a0 = qb; a1 = q0; }
  }
  float s7d = dpp_shr1_f(a7), s6d = dpp_shr1_f(a6), s5d = dpp_shr1_f(a5);
  int epd = 0;
  float corr = (lane == 0) ? 0.f : 1.f;

  // pair-round: 2 lattice steps from one 16B slot + f32 blank pair
  auto round2 = [&](uint4 rw, float2 bl, bool renorm) {
    float2 aLo = __half22float2(*(__half2*)&rw.x);
    float2 aHi = __half22float2(*(__half2*)&rw.y);
    float2 bLo = __half22float2(*(__half2*)&rw.z);
    float2 bHi = __half22float2(*(__half2*)&rw.w);
    const float qbA = bl.x, qbB = bl.y;
    const float qhA = dpp_shr1_f(aHi.y);  // halo label prob (VALU pipe)
    const float w7 = s7d * corr, w6 = s6d * corr, w5 = s5d * corr;
    const float hA = (w7 + w6 + skH * w5) * qhA;
    float n0 = (a0 + w7) * qbA;
    float n1 = (a1 + a0 + sk0 * w7) * aLo.x;
    float n2 = (a2 + a1) * qbA;
    float n3 = (a3 + a2 + sk1 * a1) * aLo.y;
    float n4 = (a4 + a3) * qbA;
    float n5 = (a5 + a4 + sk2 * a3) * aHi.x;
    float n6 = (a6 + a5) * qbA;
    float n7 = (a7 + a6 + sk3 * a5) * aHi.y;
    a0 = (n0 + hA) * qbB;
    a1 = (n1 + n0 + sk0 * hA) * bLo.x;
    a2 = (n2 + n1) * qbB;
    a3 = (n3 + n2 + sk1 * n1) * bLo.y;
    a4 = (n4 + n3) * qbB;
    a5 = (n5 + n4 + sk2 * n3) * bHi.x;
    a6 = (n6 + n5) * qbB;
    a7 = (n7 + n6 + sk3 * n5) * bHi.y;
    if (renorm) {  // every 8 steps, exact pow2
      float mx = fmaxf(fmaxf(fmaxf(a0, a1), fmaxf(a2, a3)),
                       fmaxf(fmaxf(a4, a5), fmaxf(a6, a7)));
      unsigned bits = __float_as_uint(mx);
      bool z = (bits == 0u);
      int e = (int)(bits >> 23) - 127;
      float f = __uint_as_float((254u - (bits >> 23)) << 23);  // 2^-e
      f = z ? 1.0f : f;
      a0 *= f; a1 *= f; a2 *= f; a3 *= f;
      a4 *= f; a5 *= f; a6 *= f; a7 *= f;
      E = z ? epd : (E + e);
    }
    s7d = dpp_shr1_f(a7);
    s6d = dpp_shr1_f(a6);
    s5d = dpp_shr1_f(a5);
    if (renorm) {
      epd = dpp_shr1_i(E);
      int de = epd - E;
      de = de < -126 ? -126 : (de > 60 ? 60 : de);
      corr = __int_as_float((de + 127) << 23);
      corr = (lane == 0) ? 0.0f : corr;
    }
  };

  const int R = (len - 1) >> 1;          // full pair-rounds
  const int leftover = (len - 1) & 1;
  const int PRtot = R + leftover;        // pairs touched
  const int NCg = (PRtot + CHP - 1) / CHP;
  const int cfull = R / CHP;

  load_blanks();
  if (NCg > 0) load_pairs(0, 0);
  __builtin_amdgcn_s_waitcnt(0x0f70);    // vmcnt(0): blanks + chunk0 landed
  if (NCg > 1) load_pairs(1, 1);

  uint4 raw[2];
  float2 blkp[2];
  if (NCg > 0) {  // entry prefetch: pairs 0,1 of chunk 0
    raw[0] = *(const uint4*)(&bufs[0][0 * PAIRB] + lane16);
    blkp[0] = *(const float2*)(blk_s + 0);
    raw[1] = *(const uint4*)(&bufs[0][1 * PAIRB] + lane16);
    blkp[1] = *(const float2*)(blk_s + 2);
  }

  for (int c = 0; c < cfull; ++c) {
    const char* base = &bufs[c & 1][0];
    const char* nbase = &bufs[(c + 1) & 1][0];
    const float* pb = blk_s + c * 32;
#pragma unroll
    for (int rr = 0; rr < 16; ++rr) {
      const int p = rr & 1;
      uint4 rw = raw[p];
      float2 bl = blkp[p];
      if (rr < 14) {  // prefetch 2 rounds ahead within chunk
        raw[p] = *(const uint4*)(base + (rr + 2) * PAIRB + lane16);
        blkp[p] = *(const float2*)(pb + (rr + 2) * 2);
      } else {        // cross-chunk prefetch (loads are ~13 rounds old)
        if (rr == 14) __builtin_amdgcn_s_waitcnt(0x0f70);  // vmcnt(0) only
        raw[p] = *(const uint4*)(nbase + (rr - 14) * PAIRB + lane16);
        blkp[p] = *(const float2*)(pb + 32 + (rr - 14) * 2);
      }
      round2(rw, bl, (rr & 3) == 3);
    }
    if (c + 2 < NCg) load_pairs(c & 1, c + 2);  // refill the buffer just freed
  }

  // tail: remaining pair-rounds + optional single step, from tail chunk buffer
  __builtin_amdgcn_s_waitcnt(0x0f70);
  {
    const char* tb = &bufs[cfull & 1][0];
    const float* pbT = blk_s + cfull * 32;
    const int rem = R - cfull * CHP;
    for (int r = 0; r < rem; ++r) {
      uint4 rw = *(const uint4*)(tb + r * PAIRB + lane16);
      float2 bl = *(const float2*)(pbT + 2 * r);
      round2(rw, bl, (r & 3) == 3);
    }
    if (leftover) {  // final odd step: slot A of pair R
      uint4 rw = *(const uint4*)(tb + rem * PAIRB + lane16);
      float blA = *(pbT + 2 * rem);
      float2 flo = __half22float2(*(__half2*)&rw.x);
      float2 fhi = __half22float2(*(__half2*)&rw.y);
      float s7 = dpp_shr1_f(a7);
      int ep = dpp_shr1_i(E);
      int de = ep - E;
      de = de < -126 ? -126 : (de > 60 ? 60 : de);
      float c2 = __int_as_float((de + 127) << 23);
      c2 = (lane == 0) ? 0.0f : c2;
      float w7 = s7 * c2;
      float n0 = (a0 + w7) * blA;
      float n1 = (a1 + a0 + sk0 * w7) * flo.x;
      float n2 = (a2 + a1) * blA;
      float n3 = (a3 + a2 + sk1 * a1) * flo.y;
      float n4 = (a4 + a3) * blA;
      float n5 = (a5 + a4 + sk2 * a3) * fhi.x;
      float n6 = (a6 + a5) * blA;
      float n7 = (a7 + a6 + sk3 * a5) * fhi.y;
      a0 = n0; a1 = n1; a2 = n2; a3 = n3;
      a4 = n4; a5 = n5; a6 = n6; a7 = n7;
    }
  }

  // final combine: loss = -lse(alpha[2ll], alpha[2ll-1]) in log2 domain
  int sE = 2 * ll;
  int sP = sE - 1 < 0 ? 0 : sE - 1;
  int laneA = sE >> 3, jA = sE & 7;
  int laneB = sP >> 3, jB = sP & 7;
  float va = a0;
  if (jA == 1) va = a1;
  if (jA == 2) va = a2;
  if (jA == 3) va = a3;
  if (jA == 4) va = a4;
  if (jA == 5) va = a5;
  if (jA == 6) va = a6;
  if (jA == 7) va = a7;
  float vb = a0;
  if (jB == 1) vb = a1;
  if (jB == 2) vb = a2;
  if (jB == 3) vb = a3;
  if (jB == 4) vb = a4;
  if (jB == 5) vb = a5;
  if (jB == 6) vb = a6;
  if (jB == 7) vb = a7;
  float aA = __int_as_float(__builtin_amdgcn_ds_bpermute(laneA << 2, __float_as_int(va)));
  float aB = __int_as_float(__builtin_amdgcn_ds_bpermute(laneB << 2, __float_as_int(vb)));
  int EA = __builtin_amdgcn_ds_bpermute(laneA << 2, E);
  int EB = __builtin_amdgcn_ds_bpermute(laneB << 2, E);
  if (lane == 0) {
    float l1 = (aA > 0.0f) ? (float)EA + log2f(aA) : -1e30f;
    float l2 = (aB > 0.0f) ? (float)EB + log2f(aB) : -1e30f;
    float mm = fmaxf(l1, l2);
    float v = mm + log2f(exp2f(l1 - mm) + exp2f(l2 - mm));
    out[b] = -v * LN2F;
  }
}

}  // namespace

extern "C" void kernel_launch(void* const* d_in, const int* in_sizes, int n_in,
                              void* d_out, int out_size, void* d_ws, size_t ws_size,
                              hipStream_t stream) {
  const float* y = (const float*)d_in[0];   // [64,2000,128] f32
  const int* yt = (const int*)d_in[1];      // [64,200] i32
  const int* il = (const int*)d_in[2];      // [64] i32
  const int* lb = (const int*)d_in[3];      // [64] i32
  float* out = (float*)d_out;               // [64] f32
  char* W = (char*)d_ws;                    // 64 * 1032192 B = 66.1 MB

  hipLaunchKernelGGL(pack_kernel, dim3(Tc / 4, Bc), dim3(256), 0, stream, y, yt, W);
  hipLaunchKernelGGL(ctc_alpha_kernel, dim3(Bc), dim3(64), 0, stream,
                     y, W, yt, il, lb, out);
}